// Round 2
// baseline (87.275 us; speedup 1.0000x reference)
//
#include <hip/hip_runtime.h>
#include <math.h>

// Tropical max/min-plus pseudo-matmul, LDS-free.
// out[b,u] = max_f(x[b,f] + w[f,u])  for u < 128, min_f otherwise.
//
// Structure: wave owns TM=8 rows x 64 units. x[row][k] is wave-uniform ->
// scalar loads (s_load_dwordx4), zero vector-memory cost. w[k][u] -> lane=u,
// coalesced 256B global loads; 4 waves per block share the same u-group so
// the w k-stream hits L1. No LDS, no syncthreads. max vs min is block-uniform
// (template), so no sign trick and no extra VALU.
// VALU floor: 268M v_add + 134M v_max3 lane-ops ~= 5.1 us at 78.6T lane-ops/s.

#define FEAT  512
#define UNITS 256
#define TM    8     // rows per wave

template<bool IS_MAX>
__device__ __forceinline__ void trop_body(const float* __restrict__ x,
                                          const float* __restrict__ w,
                                          float* __restrict__ out,
                                          int ubase) {
    const int lane = threadIdx.x & 63;
    const int wv   = __builtin_amdgcn_readfirstlane(threadIdx.x >> 6);  // force SGPR
    const int u    = ubase + lane;
    const int row0 = blockIdx.y * (4 * TM) + wv * TM;   // 32 rows per block

    float acc[TM];
    #pragma unroll
    for (int r = 0; r < TM; ++r) acc[r] = IS_MAX ? -__builtin_inff() : __builtin_inff();

    const float* wp = w + u;   // lane-strided column walk, row stride = UNITS

    #pragma unroll 2
    for (int k0 = 0; k0 < FEAT; k0 += 8) {
        // 8 w values for this lane's unit: 8 coalesced b32 loads (imm offsets)
        const float wk0 = wp[(k0 + 0) * UNITS];
        const float wk1 = wp[(k0 + 1) * UNITS];
        const float wk2 = wp[(k0 + 2) * UNITS];
        const float wk3 = wp[(k0 + 3) * UNITS];
        const float wk4 = wp[(k0 + 4) * UNITS];
        const float wk5 = wp[(k0 + 5) * UNITS];
        const float wk6 = wp[(k0 + 6) * UNITS];
        const float wk7 = wp[(k0 + 7) * UNITS];

        #pragma unroll
        for (int r = 0; r < TM; ++r) {
            // wave-uniform address -> scalar loads
            const float4* xr = (const float4*)(x + (size_t)(row0 + r) * FEAT + k0);
            const float4 a0 = xr[0];
            const float4 a1 = xr[1];

            const float s0 = a0.x + wk0, s1 = a0.y + wk1;
            const float s2 = a0.z + wk2, s3 = a0.w + wk3;
            const float s4 = a1.x + wk4, s5 = a1.y + wk5;
            const float s6 = a1.z + wk6, s7 = a1.w + wk7;

            if (IS_MAX) {
                const float m0 = fmaxf(fmaxf(s0, s1), s2);   // v_max3
                const float m1 = fmaxf(fmaxf(s3, s4), s5);   // v_max3
                const float m2 = fmaxf(fmaxf(s6, s7), acc[r]);
                acc[r] = fmaxf(fmaxf(m0, m1), m2);
            } else {
                const float m0 = fminf(fminf(s0, s1), s2);   // v_min3
                const float m1 = fminf(fminf(s3, s4), s5);
                const float m2 = fminf(fminf(s6, s7), acc[r]);
                acc[r] = fminf(fminf(m0, m1), m2);
            }
        }
    }

    #pragma unroll
    for (int r = 0; r < TM; ++r)
        out[(size_t)(row0 + r) * UNITS + u] = acc[r];   // 256B coalesced per row
}

__global__ __launch_bounds__(256) void tropical_kernel(const float* __restrict__ x,
                                                       const float* __restrict__ w,
                                                       float* __restrict__ out) {
    const int ubase = blockIdx.x * 64;        // 0,64 -> max region; 128,192 -> min
    if (ubase < 128) trop_body<true>(x, w, out, ubase);
    else             trop_body<false>(x, w, out, ubase);
}

extern "C" void kernel_launch(void* const* d_in, const int* in_sizes, int n_in,
                              void* d_out, int out_size, void* d_ws, size_t ws_size,
                              hipStream_t stream) {
    const float* x = (const float*)d_in[0];   // (2048, 512)
    const float* w = (const float*)d_in[1];   // (512, 256)
    float* out = (float*)d_out;               // (2048, 256)

    // 4 u-groups x 64 row-groups = 256 blocks x 4 waves = 1024 waves (1/SIMD)
    dim3 grid(UNITS / 64, 2048 / 32);
    tropical_kernel<<<grid, dim3(256), 0, stream>>>(x, w, out);
}

// Round 3
// 74.913 us; speedup vs baseline: 1.1650x; 1.1650x over previous
//
#include <hip/hip_runtime.h>
#include <math.h>

// Tropical max/min-plus pseudo-matmul, LDS-free main loop, k-split across waves.
// out[b,u] = max_f(x[b,f] + w[f,u])  for u < 128, min_f otherwise.
//
// R2 lesson: 1 wave/SIMD left VALU at 22% (latency-bound). Fix: 512-thread
// blocks, 8 waves each owning a 64-wide k-chunk of the SAME 8 rows x 64 units
// -> 8192 waves = 8/SIMD (full occupancy) with unchanged per-wave w reuse.
// x[row][k] wave-uniform -> scalar loads; w[k][u] lane=u -> coalesced 256B.
// Partial accs combined via tiny LDS tree (banks = lane%32, 2 lanes/bank = free).
// VALU floor: 268M v_add + 134M v_max3 lane-ops ~= 5.1 us.

#define FEAT  512
#define UNITS 256
#define TM    8     // rows per block (and per wave)
#define KW    64    // k-chunk per wave

template<bool IS_MAX>
__device__ __forceinline__ void trop_body(const float* __restrict__ x,
                                          const float* __restrict__ w,
                                          float* __restrict__ out,
                                          int ubase, float* __restrict__ part) {
    const int tid  = threadIdx.x;
    const int lane = tid & 63;
    const int wv   = __builtin_amdgcn_readfirstlane(tid >> 6);  // 0..7, SGPR
    const int u    = ubase + lane;
    const int row0 = blockIdx.y * TM;
    const int kbase = wv * KW;

    float acc[TM];
    #pragma unroll
    for (int r = 0; r < TM; ++r) acc[r] = IS_MAX ? -__builtin_inff() : __builtin_inff();

    const float* wp = w + (size_t)kbase * UNITS + u;
    const float* xp = x + kbase;

    #pragma unroll
    for (int i = 0; i < KW / 8; ++i) {
        const int k0 = i * 8;
        // 8 w values for this lane's unit: coalesced 256B loads, L2-resident
        const float wk0 = wp[(k0 + 0) * UNITS];
        const float wk1 = wp[(k0 + 1) * UNITS];
        const float wk2 = wp[(k0 + 2) * UNITS];
        const float wk3 = wp[(k0 + 3) * UNITS];
        const float wk4 = wp[(k0 + 4) * UNITS];
        const float wk5 = wp[(k0 + 5) * UNITS];
        const float wk6 = wp[(k0 + 6) * UNITS];
        const float wk7 = wp[(k0 + 7) * UNITS];

        #pragma unroll
        for (int r = 0; r < TM; ++r) {
            // wave-uniform address -> scalar loads (s_load_dwordx4)
            const float4* xr = (const float4*)(xp + (size_t)(row0 + r) * FEAT + k0);
            const float4 a0 = xr[0];
            const float4 a1 = xr[1];

            const float s0 = a0.x + wk0, s1 = a0.y + wk1;
            const float s2 = a0.z + wk2, s3 = a0.w + wk3;
            const float s4 = a1.x + wk4, s5 = a1.y + wk5;
            const float s6 = a1.z + wk6, s7 = a1.w + wk7;

            if (IS_MAX) {
                const float m0 = fmaxf(fmaxf(s0, s1), s2);     // v_max3
                const float m1 = fmaxf(fmaxf(s3, s4), s5);     // v_max3
                const float m2 = fmaxf(fmaxf(s6, s7), acc[r]); // v_max3
                acc[r] = fmaxf(fmaxf(m0, m1), m2);             // v_max3
            } else {
                const float m0 = fminf(fminf(s0, s1), s2);
                const float m1 = fminf(fminf(s3, s4), s5);
                const float m2 = fminf(fminf(s6, s7), acc[r]);
                acc[r] = fminf(fminf(m0, m1), m2);
            }
        }
    }

    // ---- combine 8 k-partials via LDS ----
    #pragma unroll
    for (int r = 0; r < TM; ++r)
        part[(wv * TM + r) * 64 + lane] = acc[r];
    __syncthreads();

    const int r = tid >> 6;  // wave wv reduces row r == wv
    float v = part[r * 64 + lane];
    #pragma unroll
    for (int j = 1; j < 8; ++j) {
        const float p = part[(j * TM + r) * 64 + lane];
        v = IS_MAX ? fmaxf(v, p) : fminf(v, p);
    }
    out[(size_t)(row0 + r) * UNITS + u] = v;   // 256B coalesced per wave
}

__global__ __launch_bounds__(512, 8) void tropical_kernel(const float* __restrict__ x,
                                                          const float* __restrict__ w,
                                                          float* __restrict__ out) {
    __shared__ float part[8 * TM * 64];        // 16 KB
    const int ubase = blockIdx.x * 64;         // 0,64 -> max; 128,192 -> min
    if (ubase < 128) trop_body<true>(x, w, out, ubase, part);
    else             trop_body<false>(x, w, out, ubase, part);
}

extern "C" void kernel_launch(void* const* d_in, const int* in_sizes, int n_in,
                              void* d_out, int out_size, void* d_ws, size_t ws_size,
                              hipStream_t stream) {
    const float* x = (const float*)d_in[0];   // (2048, 512)
    const float* w = (const float*)d_in[1];   // (512, 256)
    float* out = (float*)d_out;               // (2048, 256)

    // 4 u-groups x 256 row-groups = 1024 blocks x 8 waves = 8192 waves = 8/SIMD
    dim3 grid(UNITS / 64, 2048 / TM);
    tropical_kernel<<<grid, dim3(512), 0, stream>>>(x, w, out);
}